// Round 1
// baseline (9333.211 us; speedup 1.0000x reference)
//
#include <hip/hip_runtime.h>
#include <stdint.h>

#define B_   256
#define T_   160
#define DIN_ 40
#define H_   768
#define NG_  3072   // 4*H
#define KP0_ 832    // 48 (x pad) + 768 + 16 pad
#define KP12_ 1536
#define XC_  48     // padded x columns

typedef _Float16 f16;
typedef _Float16 half8 __attribute__((ext_vector_type(8)));
typedef float f32x4 __attribute__((ext_vector_type(4)));

#define AS1C(p) ((const __attribute__((address_space(1))) uint32_t*)(p))
#define AS3(p)  ((__attribute__((address_space(3))) uint32_t*)(p))

struct Params {
  const f16* wt0; const f16* wt1; const f16* wt2;
  const float* bq; const f16* x16;
  f16* hs0; f16* hs1; f16* hs2;
  float* cst; const f16* zpad; unsigned* cnt; float* out;
};

__device__ __forceinline__ float sigmoid_f(float x) { return 1.f / (1.f + __expf(-x)); }
__device__ __forceinline__ float tanh_f(float x) {
  x = fminf(15.f, fmaxf(-15.f, x));
  float e = __expf(2.f * x);
  return (e - 1.f) / (e + 1.f);
}

// Convert weights to fp16, transposed to [n'][k] with gate-interleaved columns
// n' = 4*j + g  <=>  original column g*768 + j.  k: [0,in_dim)=Wi, [hoff,hoff+768)=Wh, else 0.
__global__ void conv_w(const float* __restrict__ Wi, const float* __restrict__ Wh,
                       int in_dim, int hoff, int Kp, f16* __restrict__ dst) {
  __shared__ f16 tile[64][66];
  const int k0 = blockIdx.x * 64;
  const int by = blockIdx.y;            // 0..47
  const int g = by / 12, j0 = (by % 12) * 64;
  const int tid = threadIdx.x;
  #pragma unroll
  for (int it = 0; it < 16; ++it) {
    int idx = it * 256 + tid;
    int jj = idx & 63;
    int kk = idx >> 6;
    int k = k0 + kk;
    int oc = g * H_ + j0 + jj;
    float v = 0.f;
    if (k < in_dim) v = Wi[(size_t)k * NG_ + oc];
    else if (k >= hoff && k < hoff + H_) v = Wh[(size_t)(k - hoff) * NG_ + oc];
    tile[kk][jj] = (f16)v;
  }
  __syncthreads();
  #pragma unroll
  for (int it = 0; it < 16; ++it) {
    int idx = it * 256 + tid;
    int kk = idx & 63;
    int jj = idx >> 6;
    int np = 4 * (j0 + jj) + g;
    dst[(size_t)np * Kp + k0 + kk] = tile[kk][jj];
  }
}

__global__ void conv_b(const float* __restrict__ b0, const float* __restrict__ b1,
                       const float* __restrict__ b2, float* __restrict__ bq) {
  int id = blockIdx.x * 256 + threadIdx.x;
  if (id < 3 * NG_) {
    int l = id / NG_, np = id % NG_;
    int j = np >> 2, g = np & 3;
    const float* s = (l == 0) ? b0 : (l == 1 ? b1 : b2);
    bq[id] = s[g * H_ + j];
  }
}

// x [B,T,40] fp32 -> x16 [T,B,48] fp16 (cols 40..47 zero)
__global__ void conv_x(const float* __restrict__ x, f16* __restrict__ x16) {
  int id = blockIdx.x * 256 + threadIdx.x;
  if (id >= T_ * B_ * XC_) return;
  int k = id % XC_;
  int b = (id / XC_) % B_;
  int t = id / (XC_ * B_);
  float v = (k < DIN_) ? x[(size_t)b * (T_ * DIN_) + t * DIN_ + k] : 0.f;
  x16[id] = (f16)v;
}

// Per-btile-group barrier (32 WGs). All cross-WG data was written with
// agent-scope atomic stores (bypass L2) into never-before-read addresses,
// so no cache invalidation is required here.
__device__ __forceinline__ void gbar(unsigned* c, unsigned target) {
  asm volatile("s_waitcnt vmcnt(0)" ::: "memory");
  __syncthreads();
  if (threadIdx.x == 0) {
    __hip_atomic_fetch_add(c, 1u, __ATOMIC_RELEASE, __HIP_MEMORY_SCOPE_AGENT);
    while (__hip_atomic_load(c, __ATOMIC_RELAXED, __HIP_MEMORY_SCOPE_AGENT) < target)
      __builtin_amdgcn_s_sleep(2);
  }
  __syncthreads();
  asm volatile("" ::: "memory");
}

__global__ __launch_bounds__(256, 1) void lstm_main(Params p) {
  __shared__ __align__(16) f16 Alds[32 * 64];    // 4 KB  : A tile [32 rows][64 k]
  __shared__ __align__(16) f16 Blds[96 * 64];    // 12 KB : B tile [96 cols][64 k]
  __shared__ __align__(16) float zbuf[32][100];  // 12.5 KB

  const int tid = threadIdx.x;
  const int lane = tid & 63;
  const int w = tid >> 6;
  const int bid = blockIdx.x;
  const int xcd = bid & 7, ii = bid >> 3;
  const int ntile = xcd * 4 + (ii >> 3);   // 0..31  (96 gate-cols = 24 h-cols)
  const int btile = ii & 7;                // 0..7   (32 batches)
  unsigned* cbar = p.cnt + btile * 32;

  const int arow_l = 16 * (w & 1) + (lane & 15);
  const int bcol_base = 48 * (w >> 1);
  const int n0 = ntile * 96;
  unsigned iter = 0;

  for (int l = 0; l < 3; ++l) {
    const f16* WT; const f16* hin; f16* hown; int Kp, nks;
    if (l == 0)      { WT = p.wt0; hin = p.x16; hown = p.hs0; Kp = KP0_;  nks = 13; }
    else if (l == 1) { WT = p.wt1; hin = p.hs0; hown = p.hs1; Kp = KP12_; nks = 24; }
    else             { WT = p.wt2; hin = p.hs1; hown = p.hs2; Kp = KP12_; nks = 24; }
    const float* bqr = p.bq + l * NG_ + n0;

    for (int t = 0; t < T_; ++t) {
      f32x4 acc0 = {0.f,0.f,0.f,0.f}, acc1 = {0.f,0.f,0.f,0.f}, acc2 = {0.f,0.f,0.f,0.f};
      for (int ks = 0; ks < nks; ++ks) {
        // ---- stage A tile: 256 x 16B chunks, one per thread (linear LDS dest,
        //      inverse-XOR-swizzled global source)
        {
          int r = tid >> 3;
          int cd = tid & 7;
          int cg = cd ^ (r & 7);
          int kchunk = ks * 8 + cg;
          int b = btile * 32 + r;
          const f16* src;
          if (l == 0) {
            if (kchunk < 6)        src = p.x16 + ((size_t)t * B_ + b) * XC_ + kchunk * 8;
            else if (kchunk < 102) src = hown + ((size_t)t * B_ + b) * H_ + (kchunk - 6) * 8;
            else                   src = p.zpad;
          } else {
            if (kchunk < 96)       src = hin + ((size_t)(t + 1) * B_ + b) * H_ + kchunk * 8;
            else                   src = hown + ((size_t)t * B_ + b) * H_ + (kchunk - 96) * 8;
          }
          __builtin_amdgcn_global_load_lds(AS1C(src), AS3(&Alds[w * 512]), 16, 0, 0);
        }
        // ---- stage B tile: 768 chunks, 3 per thread
        #pragma unroll
        for (int itb = 0; itb < 3; ++itb) {
          int cid = itb * 256 + tid;
          int rr = cid >> 3;
          int cd2 = cid & 7;
          int cg2 = cd2 ^ (rr & 7);
          const f16* srcb = WT + (size_t)(n0 + rr) * Kp + ks * 64 + cg2 * 8;
          __builtin_amdgcn_global_load_lds(AS1C(srcb), AS3(&Blds[itb * 2048 + w * 512]), 16, 0, 0);
        }
        asm volatile("s_waitcnt vmcnt(0)" ::: "memory");
        __syncthreads();
        // ---- MFMA: wave tile [16 rows x 48 cols], K=64 in two 32-k halves
        {
          const char* Ab = (const char*)Alds;
          const char* Bb = (const char*)Blds;
          #pragma unroll
          for (int kk2 = 0; kk2 < 2; ++kk2) {
            int chunk = kk2 * 4 + (lane >> 4);
            half8 a = *(const half8*)(Ab + arow_l * 128 + ((chunk ^ (arow_l & 7)) * 16));
            int bc0 = bcol_base + (lane & 15);
            half8 bv0 = *(const half8*)(Bb + bc0 * 128 + ((chunk ^ (bc0 & 7)) * 16));
            acc0 = __builtin_amdgcn_mfma_f32_16x16x32_f16(a, bv0, acc0, 0, 0, 0);
            int bc1 = bc0 + 16;
            half8 bv1 = *(const half8*)(Bb + bc1 * 128 + ((chunk ^ (bc1 & 7)) * 16));
            acc1 = __builtin_amdgcn_mfma_f32_16x16x32_f16(a, bv1, acc1, 0, 0, 0);
            int bc2 = bc0 + 32;
            half8 bv2 = *(const half8*)(Bb + bc2 * 128 + ((chunk ^ (bc2 & 7)) * 16));
            acc2 = __builtin_amdgcn_mfma_f32_16x16x32_f16(a, bv2, acc2, 0, 0, 0);
          }
        }
        __syncthreads();
      }
      // ---- epilogue: Z (+bias) -> LDS
      {
        int rbase = 16 * (w & 1) + (lane >> 4) * 4;
        int cb = bcol_base + (lane & 15);
        #pragma unroll
        for (int r4 = 0; r4 < 4; ++r4) {
          zbuf[rbase + r4][cb]      = acc0[r4] + bqr[cb];
          zbuf[rbase + r4][cb + 16] = acc1[r4] + bqr[cb + 16];
          zbuf[rbase + r4][cb + 32] = acc2[r4] + bqr[cb + 32];
        }
      }
      __syncthreads();
      // ---- gates: 384 items (32 rows x 12 j-pairs), h stored as agent-scope u32
      #pragma unroll
      for (int it = 0; it < 2; ++it) {
        int id = it * 256 + tid;
        if (id < 384) {
          int row = id / 12;
          int jp = id - row * 12;
          int b = btile * 32 + row;
          int hc0 = ntile * 24 + 2 * jp;
          const float* zp = &zbuf[row][8 * jp];
          float c0 = 0.f, c1 = 0.f;
          float* cp = p.cst + (size_t)b * H_ + hc0;
          if (t > 0) { c0 = cp[0]; c1 = cp[1]; }
          float i0 = sigmoid_f(zp[0]), f0 = sigmoid_f(zp[1]);
          float g0 = tanh_f(zp[2]),    o0 = sigmoid_f(zp[3]);
          float i1 = sigmoid_f(zp[4]), f1 = sigmoid_f(zp[5]);
          float g1 = tanh_f(zp[6]),    o1 = sigmoid_f(zp[7]);
          float cn0 = f0 * c0 + i0 * g0;
          float cn1 = f1 * c1 + i1 * g1;
          cp[0] = cn0; cp[1] = cn1;
          float h0 = o0 * tanh_f(cn0);
          float h1 = o1 * tanh_f(cn1);
          f16 hh0 = (f16)h0, hh1 = (f16)h1;
          unsigned u = ((unsigned)__builtin_bit_cast(uint16_t, hh1) << 16)
                     |  (unsigned)__builtin_bit_cast(uint16_t, hh0);
          unsigned* hp = (unsigned*)(hown + ((size_t)(t + 1) * B_ + b) * H_ + hc0);
          __hip_atomic_store(hp, u, __ATOMIC_RELAXED, __HIP_MEMORY_SCOPE_AGENT);
          if (l == 2) {
            float* op = p.out + (size_t)b * H_ + hc0;
            if (t == 0) { op[0] = h0 * (1.f / T_); op[1] = h1 * (1.f / T_); }
            else        { op[0] += h0 * (1.f / T_); op[1] += h1 * (1.f / T_); }
          }
        }
      }
      iter++;
      gbar(cbar, 32u * iter);
    }
  }
}

extern "C" void kernel_launch(void* const* d_in, const int* in_sizes, int n_in,
                              void* d_out, int out_size, void* d_ws, size_t ws_size,
                              hipStream_t stream) {
  const float* x   = (const float*)d_in[0];
  const float* Wi0 = (const float*)d_in[1];
  const float* Wh0 = (const float*)d_in[2];
  const float* b0  = (const float*)d_in[3];
  const float* Wi1 = (const float*)d_in[4];
  const float* Wh1 = (const float*)d_in[5];
  const float* b1  = (const float*)d_in[6];
  const float* Wi2 = (const float*)d_in[7];
  const float* Wh2 = (const float*)d_in[8];
  const float* b2  = (const float*)d_in[9];

  char* wsb = (char*)d_ws;
  size_t off = 0;
  auto nxt = [&](size_t sz) { char* p = wsb + off; off += (sz + 255) & ~(size_t)255; return p; };
  f16*      wt0  = (f16*)nxt((size_t)NG_ * KP0_ * 2);        // 5.1 MB
  f16*      wt1  = (f16*)nxt((size_t)NG_ * KP12_ * 2);       // 9.4 MB
  f16*      wt2  = (f16*)nxt((size_t)NG_ * KP12_ * 2);       // 9.4 MB
  float*    bq   = (float*)nxt((size_t)3 * NG_ * 4);
  f16*      x16  = (f16*)nxt((size_t)T_ * B_ * XC_ * 2);     // 3.9 MB
  f16*      hs0  = (f16*)nxt((size_t)(T_ + 1) * B_ * H_ * 2); // 63.3 MB
  f16*      hs1  = (f16*)nxt((size_t)(T_ + 1) * B_ * H_ * 2);
  f16*      hs2  = (f16*)nxt((size_t)(T_ + 1) * B_ * H_ * 2);
  float*    cst  = (float*)nxt((size_t)B_ * H_ * 4);
  f16*      zpad = (f16*)nxt(256);
  unsigned* cnt  = (unsigned*)nxt(1024);
  if (off > ws_size) return;  // insufficient workspace

  const size_t slot_bytes = (size_t)B_ * H_ * 2;
  hipMemsetAsync(hs0, 0, slot_bytes, stream);
  hipMemsetAsync(hs1, 0, slot_bytes, stream);
  hipMemsetAsync(hs2, 0, slot_bytes, stream);
  hipMemsetAsync((void*)zpad, 0, 256, stream);
  hipMemsetAsync(cnt, 0, 1024, stream);

  hipLaunchKernelGGL(conv_w, dim3(KP0_ / 64, 48), dim3(256), 0, stream, Wi0, Wh0, DIN_, XC_, KP0_, wt0);
  hipLaunchKernelGGL(conv_w, dim3(KP12_ / 64, 48), dim3(256), 0, stream, Wi1, Wh1, H_, H_, KP12_, wt1);
  hipLaunchKernelGGL(conv_w, dim3(KP12_ / 64, 48), dim3(256), 0, stream, Wi2, Wh2, H_, H_, KP12_, wt2);
  hipLaunchKernelGGL(conv_b, dim3((3 * NG_ + 255) / 256), dim3(256), 0, stream, b0, b1, b2, bq);
  hipLaunchKernelGGL(conv_x, dim3((T_ * B_ * XC_ + 255) / 256), dim3(256), 0, stream, x, x16);

  Params prm{wt0, wt1, wt2, bq, x16, hs0, hs1, hs2, cst, zpad, cnt, (float*)d_out};
  void* kargs[] = { &prm };
  hipLaunchCooperativeKernel((void*)lstm_main, dim3(256), dim3(256), kargs, 0, stream);
}

// Round 4
// 7626.356 us; speedup vs baseline: 1.2238x; 1.2238x over previous
//
#include <hip/hip_runtime.h>
#include <stdint.h>

#define B_   256
#define T_   160
#define DIN_ 40
#define H_   768
#define NG_  3072   // 4*H
#define KP0_ 1024   // 40 x (+8 pad) | 768 h | pad to 1024
#define KP12_ 1536  // 768 hin | 768 hown
#define XC_  48     // padded x columns

typedef _Float16 f16;
typedef _Float16 half8 __attribute__((ext_vector_type(8)));
typedef float f32x4 __attribute__((ext_vector_type(4)));

#define AS1C(p) ((const __attribute__((address_space(1))) uint32_t*)(p))
#define AS3(p)  ((__attribute__((address_space(3))) uint32_t*)(p))

struct Params {
  const f16* wt0; const f16* wt1; const f16* wt2;
  const float* bq; const f16* x16;
  f16* hs0; f16* hs1; f16* hs2;
  const f16* zpad; unsigned* cnt; float* out;
};

__device__ __forceinline__ float sigmoid_f(float x) { return 1.f / (1.f + __expf(-x)); }
__device__ __forceinline__ float tanh_f(float x) {
  x = fminf(15.f, fmaxf(-15.f, x));
  float e = __expf(2.f * x);
  return (e - 1.f) / (e + 1.f);
}

// Weights -> fp16, transposed [n'][k], gate-interleaved cols n' = 4*j + g.
// k: [0,in_dim)=Wi rows, [hoff,hoff+768)=Wh rows, else 0.
__global__ void conv_w(const float* __restrict__ Wi, const float* __restrict__ Wh,
                       int in_dim, int hoff, int Kp, f16* __restrict__ dst) {
  __shared__ f16 tile[64][66];
  const int k0 = blockIdx.x * 64;
  const int by = blockIdx.y;            // 0..47
  const int g = by / 12, j0 = (by % 12) * 64;
  const int tid = threadIdx.x;
  #pragma unroll
  for (int it = 0; it < 16; ++it) {
    int idx = it * 256 + tid;
    int jj = idx & 63;
    int kk = idx >> 6;
    int k = k0 + kk;
    int oc = g * H_ + j0 + jj;
    float v = 0.f;
    if (k < in_dim) v = Wi[(size_t)k * NG_ + oc];
    else if (k >= hoff && k < hoff + H_) v = Wh[(size_t)(k - hoff) * NG_ + oc];
    tile[kk][jj] = (f16)v;
  }
  __syncthreads();
  #pragma unroll
  for (int it = 0; it < 16; ++it) {
    int idx = it * 256 + tid;
    int kk = idx & 63;
    int jj = idx >> 6;
    int np = 4 * (j0 + jj) + g;
    dst[(size_t)np * Kp + k0 + kk] = tile[kk][jj];
  }
}

__global__ void conv_b(const float* __restrict__ b0, const float* __restrict__ b1,
                       const float* __restrict__ b2, float* __restrict__ bq) {
  int id = blockIdx.x * 256 + threadIdx.x;
  if (id < 3 * NG_) {
    int l = id / NG_, np = id % NG_;
    int j = np >> 2, g = np & 3;
    const float* s = (l == 0) ? b0 : (l == 1 ? b1 : b2);
    bq[id] = s[g * H_ + j];
  }
}

// x [B,T,40] fp32 -> x16 [T,B,48] fp16 (cols 40..47 zero)
__global__ void conv_x(const float* __restrict__ x, f16* __restrict__ x16) {
  int id = blockIdx.x * 256 + threadIdx.x;
  if (id >= T_ * B_ * XC_) return;
  int k = id % XC_;
  int b = (id / XC_) % B_;
  int t = id / (XC_ * B_);
  float v = (k < DIN_) ? x[(size_t)b * (T_ * DIN_) + t * DIN_ + k] : 0.f;
  x16[id] = (f16)v;
}

// gates for one (row, jp) item: 8 gate-cols = 2 h-cols. c/out-acc live in caller regs.
template<bool LAST>
__device__ __forceinline__ void gate_item(int row, int jp, float& c0, float& c1,
    float& oa0, float& oa1, const float* zred, const float* bqs,
    f16* hown, float* out, int btile, int ntile, int t) {
  const float* z0 = zred + (size_t)row * 100 + jp * 8;
  const float* z1 = z0 + 3200;
  f32x4 qa = *(const f32x4*)z0;
  f32x4 qb = *(const f32x4*)(z0 + 4);
  f32x4 ra = *(const f32x4*)z1;
  f32x4 rb = *(const f32x4*)(z1 + 4);
  f32x4 ba = *(const f32x4*)(bqs + jp * 8);
  f32x4 bb = *(const f32x4*)(bqs + jp * 8 + 4);
  f32x4 za = qa + ra + ba;
  f32x4 zb = qb + rb + bb;
  float i0 = sigmoid_f(za[0]), f0 = sigmoid_f(za[1]), g0 = tanh_f(za[2]), o0 = sigmoid_f(za[3]);
  float i1 = sigmoid_f(zb[0]), f1 = sigmoid_f(zb[1]), g1 = tanh_f(zb[2]), o1 = sigmoid_f(zb[3]);
  float cn0 = f0 * c0 + i0 * g0;
  float cn1 = f1 * c1 + i1 * g1;
  c0 = cn0; c1 = cn1;
  float h0 = o0 * tanh_f(cn0);
  float h1 = o1 * tanh_f(cn1);
  int b = btile * 32 + row;
  int hc0 = ntile * 24 + 2 * jp;
  f16 hh0 = (f16)h0, hh1 = (f16)h1;
  unsigned u = ((unsigned)__builtin_bit_cast(uint16_t, hh1) << 16)
             |  (unsigned)__builtin_bit_cast(uint16_t, hh0);
  unsigned* hp = (unsigned*)(hown + ((size_t)(t + 1) * B_ + b) * H_ + hc0);
  __hip_atomic_store(hp, u, __ATOMIC_RELAXED, __HIP_MEMORY_SCOPE_AGENT);
  if (LAST) {
    oa0 += h0; oa1 += h1;
    if (t == T_ - 1) {
      out[(size_t)b * H_ + hc0]     = oa0 * (1.f / T_);
      out[(size_t)b * H_ + hc0 + 1] = oa1 * (1.f / T_);
    }
  }
}

template<int L>
__device__ __forceinline__ void run_layer(
    const f16* __restrict__ WT, const f16* __restrict__ hin, f16* __restrict__ hown,
    const float* __restrict__ bql, const f16* __restrict__ zpad, float* __restrict__ out,
    unsigned* cbar, unsigned& iter, f16* Abuf, float* zred, float* bqs,
    int tid, int lane, int w, int kw, int cw, int btile, int ntile, int n0) {
  constexpr int KP    = (L == 0) ? KP0_ : KP12_;
  constexpr int NKT   = (L == 0) ? 16 : 24;      // 32-k tiles per wave (k-half)
  constexpr int KHALF = (L == 0) ? 512 : 768;
  // 16B chunks per A row IN THE ADDRESSED BLOCK: layer 0 stages one 32x1024
  // block (128 chunks/row); layers 1/2 stage two half-blocks of 32x768
  // (96 chunks/row each) -- row stride must be 96 chunks, not 192.
  constexpr int CH    = (L == 0) ? 128 : 96;

  if (tid < 96) bqs[tid] = bql[tid];

  // ---- persistent B fragments: 3 col-tiles x NKT k-tiles, 4 VGPR each
  half8 breg[3 * NKT];
  #pragma unroll
  for (int ct = 0; ct < 3; ++ct) {
    #pragma unroll
    for (int kt = 0; kt < NKT; ++kt) {
      int col = n0 + cw * 48 + ct * 16 + (lane & 15);
      int k = kw * KHALF + kt * 32 + (lane >> 4) * 8;
      breg[ct * NKT + kt] = *(const half8*)(WT + (size_t)col * KP + k);
    }
  }

  // Ain staging (kw0 waves, layers 1/2): hin(t+1) -> slot tt+1. hin is the
  // PREVIOUS layer's output, fully written before this layer starts, so this
  // prefetch needs no barrier protection.
  auto stage_ain = [&](int tt) {
    #pragma unroll
    for (int i = 0; i < 24; ++i) {
      int cb = (w & 1) * 1536 + i * 64;     // uniform per wave
      int idx = cb + lane;
      int row = idx / 96;
      int c = idx - row * 96;
      int cg = c ^ (row & 7);
      int b = btile * 32 + row;
      const f16* src = hin + ((size_t)(tt + 1) * B_ + b) * H_ + cg * 8;
      __builtin_amdgcn_global_load_lds(AS1C(src), AS3(Abuf + (size_t)cb * 8), 16, 0, 0);
    }
  };
  if (L > 0 && kw == 0) stage_ain(0);

  // thread-private cell state + mean accumulators (same items every step)
  float cA0 = 0.f, cA1 = 0.f, cB0 = 0.f, cB1 = 0.f;
  float oA0 = 0.f, oA1 = 0.f, oB0 = 0.f, oB1 = 0.f;
  const int rowA = tid / 12, jpA = tid - rowA * 12;
  const bool hasB = tid < 128;
  const int idB = 256 + tid;
  const int rowB = idB / 12, jpB = idB - rowB * 12;

  for (int t = 0; t < T_; ++t) {
    // ---- stage dynamic A part
    if (L == 0) {
      #pragma unroll
      for (int i = 0; i < 16; ++i) {
        int cb = w * 1024 + i * 64;
        int idx = cb + lane;
        int row = idx >> 7;
        int c = idx & 127;
        int cg = c ^ (row & 7);
        int b = btile * 32 + row;
        const f16* src;
        if (cg < 6)        src = hin + ((size_t)t * B_ + b) * XC_ + cg * 8;       // x16
        else if (cg < 102) src = hown + ((size_t)t * B_ + b) * H_ + (cg - 6) * 8;
        else               src = zpad;
        __builtin_amdgcn_global_load_lds(AS1C(src), AS3(Abuf + (size_t)cb * 8), 16, 0, 0);
      }
    } else if (kw == 1) {
      #pragma unroll
      for (int i = 0; i < 24; ++i) {
        int cb = (w & 1) * 1536 + i * 64;
        int idx = cb + lane;
        int row = idx / 96;
        int c = idx - row * 96;
        int cg = c ^ (row & 7);
        int b = btile * 32 + row;
        const f16* src = hown + ((size_t)t * B_ + b) * H_ + cg * 8;
        __builtin_amdgcn_global_load_lds(AS1C(src), AS3(Abuf + (size_t)(32 * 768 + cb * 8)), 16, 0, 0);
      }
    }
    asm volatile("s_waitcnt vmcnt(0)" ::: "memory");
    __syncthreads();

    // ---- MFMA: wave tile 32 rows x 48 cols over its k-half
    f32x4 acc[2][3] = {};
    const char* Ab = (const char*)(Abuf + (L == 0 ? 0 : kw * 32 * 768));
    #pragma unroll
    for (int kt = 0; kt < NKT; ++kt) {
      half8 a0, a1;
      {
        int row = (lane & 15);
        int c = (L == 0 ? kw * 64 : 0) + kt * 4 + (lane >> 4);
        a0 = *(const half8*)(Ab + (size_t)row * (CH * 16) + (size_t)(c ^ (row & 7)) * 16);
        int row1 = 16 + (lane & 15);
        a1 = *(const half8*)(Ab + (size_t)row1 * (CH * 16) + (size_t)(c ^ (row1 & 7)) * 16);
      }
      #pragma unroll
      for (int ct = 0; ct < 3; ++ct) {
        acc[0][ct] = __builtin_amdgcn_mfma_f32_16x16x32_f16(a0, breg[ct * NKT + kt], acc[0][ct], 0, 0, 0);
        acc[1][ct] = __builtin_amdgcn_mfma_f32_16x16x32_f16(a1, breg[ct * NKT + kt], acc[1][ct], 0, 0, 0);
      }
    }

    // ---- partial Z -> LDS (2 k-halves reduced in gate phase)
    {
      float* zr = zred + (size_t)kw * 3200;
      #pragma unroll
      for (int rt = 0; rt < 2; ++rt) {
        #pragma unroll
        for (int ct = 0; ct < 3; ++ct) {
          int row = rt * 16 + (lane >> 4) * 4;
          int col = cw * 48 + ct * 16 + (lane & 15);
          #pragma unroll
          for (int r4 = 0; r4 < 4; ++r4)
            zr[(size_t)(row + r4) * 100 + col] = acc[rt][ct][r4];
        }
      }
    }
    __syncthreads();

    // ---- gates + h + (layer2) mean accumulation
    gate_item<L == 2>(rowA, jpA, cA0, cA1, oA0, oA1, zred, bqs, hown, out, btile, ntile, t);
    if (hasB)
      gate_item<L == 2>(rowB, jpB, cB0, cB1, oB0, oB1, zred, bqs, hown, out, btile, ntile, t);

    // ---- group barrier (32 WGs of this btile); prefetch hin(t+2) during spin
    asm volatile("s_waitcnt vmcnt(0)" ::: "memory");
    __syncthreads();
    if (L > 0 && kw == 0 && t + 1 < T_) stage_ain(t + 1);
    ++iter;
    if (tid == 255) {  // master in wave 3 (no prefetch outstanding)
      __hip_atomic_fetch_add(cbar, 1u, __ATOMIC_RELEASE, __HIP_MEMORY_SCOPE_AGENT);
      while (__hip_atomic_load(cbar, __ATOMIC_RELAXED, __HIP_MEMORY_SCOPE_AGENT) < 32u * iter)
        __builtin_amdgcn_s_sleep(2);
    }
    __syncthreads();
  }
}

__global__ __launch_bounds__(256, 1) void lstm_main(Params p) {
  __shared__ __align__(16) f16 Abuf[2 * 32 * 768];        // 96 KB
  __shared__ __align__(16) float zred[2 * 32 * 100];      // 25.6 KB
  __shared__ __align__(16) float bqs[96];

  const int tid = threadIdx.x;
  const int lane = tid & 63;
  const int w = tid >> 6;
  const int kw = w >> 1, cw = w & 1;
  const int bid = blockIdx.x;
  // CONTIGUOUS group mapping: group = 32 consecutive bids. With sequential HW
  // dispatch this guarantees whole groups become resident together, so each
  // independent group completes (and frees CUs) even if not all 256 WGs fit.
  const int btile = bid >> 5;              // 0..7
  const int ntile = bid & 31;              // 0..31
  unsigned* cbar = p.cnt + btile * 32;
  const int n0 = ntile * 96;
  unsigned iter = 0;

  run_layer<0>(p.wt0, p.x16, p.hs0, p.bq + 0 * NG_ + n0, p.zpad, p.out, cbar, iter,
               Abuf, zred, bqs, tid, lane, w, kw, cw, btile, ntile, n0);
  run_layer<1>(p.wt1, p.hs0, p.hs1, p.bq + 1 * NG_ + n0, p.zpad, p.out, cbar, iter,
               Abuf, zred, bqs, tid, lane, w, kw, cw, btile, ntile, n0);
  run_layer<2>(p.wt2, p.hs1, p.hs2, p.bq + 2 * NG_ + n0, p.zpad, p.out, cbar, iter,
               Abuf, zred, bqs, tid, lane, w, kw, cw, btile, ntile, n0);
}

extern "C" void kernel_launch(void* const* d_in, const int* in_sizes, int n_in,
                              void* d_out, int out_size, void* d_ws, size_t ws_size,
                              hipStream_t stream) {
  const float* x   = (const float*)d_in[0];
  const float* Wi0 = (const float*)d_in[1];
  const float* Wh0 = (const float*)d_in[2];
  const float* b0  = (const float*)d_in[3];
  const float* Wi1 = (const float*)d_in[4];
  const float* Wh1 = (const float*)d_in[5];
  const float* b1  = (const float*)d_in[6];
  const float* Wi2 = (const float*)d_in[7];
  const float* Wh2 = (const float*)d_in[8];
  const float* b2  = (const float*)d_in[9];

  char* wsb = (char*)d_ws;
  size_t off = 0;
  auto nxt = [&](size_t sz) { char* p = wsb + off; off += (sz + 255) & ~(size_t)255; return p; };
  f16*      wt0  = (f16*)nxt((size_t)NG_ * KP0_ * 2);         // 6.3 MB
  f16*      wt1  = (f16*)nxt((size_t)NG_ * KP12_ * 2);        // 9.4 MB
  f16*      wt2  = (f16*)nxt((size_t)NG_ * KP12_ * 2);        // 9.4 MB
  float*    bq   = (float*)nxt((size_t)3 * NG_ * 4);
  f16*      x16  = (f16*)nxt((size_t)T_ * B_ * XC_ * 2);      // 3.9 MB
  f16*      hs0  = (f16*)nxt((size_t)(T_ + 1) * B_ * H_ * 2); // 60.4 MB
  f16*      hs1  = (f16*)nxt((size_t)(T_ + 1) * B_ * H_ * 2);
  f16*      hs2  = (f16*)nxt((size_t)(T_ + 1) * B_ * H_ * 2);
  f16*      zpad = (f16*)nxt(256);
  unsigned* cnt  = (unsigned*)nxt(1024);
  if (off > ws_size) return;  // insufficient workspace

  const size_t slot_bytes = (size_t)B_ * H_ * 2;
  hipMemsetAsync(hs0, 0, slot_bytes, stream);
  hipMemsetAsync(hs1, 0, slot_bytes, stream);
  hipMemsetAsync(hs2, 0, slot_bytes, stream);
  hipMemsetAsync((void*)zpad, 0, 256, stream);
  hipMemsetAsync(cnt, 0, 1024, stream);

  hipLaunchKernelGGL(conv_w, dim3(KP0_ / 64, 48), dim3(256), 0, stream, Wi0, Wh0, DIN_, XC_, KP0_, wt0);
  hipLaunchKernelGGL(conv_w, dim3(KP12_ / 64, 48), dim3(256), 0, stream, Wi1, Wh1, H_, H_, KP12_, wt1);
  hipLaunchKernelGGL(conv_w, dim3(KP12_ / 64, 48), dim3(256), 0, stream, Wi2, Wh2, H_, H_, KP12_, wt2);
  hipLaunchKernelGGL(conv_b, dim3((3 * NG_ + 255) / 256), dim3(256), 0, stream, b0, b1, b2, bq);
  hipLaunchKernelGGL(conv_x, dim3((T_ * B_ * XC_ + 255) / 256), dim3(256), 0, stream, x, x16);

  Params prm{wt0, wt1, wt2, bq, x16, hs0, hs1, hs2, zpad, cnt, (float*)d_out};
  // Plain launch (NOT cooperative): no grid-wide sync is used, only the 8
  // independent 32-WG group barriers. Cooperative-launch validation silently
  // rejected this kernel at 122 KB LDS / 1 WG-per-CU (rounds 2-3: zero output).
  hipLaunchKernelGGL(lstm_main, dim3(256), dim3(256), 0, stream, prm);
}

// Round 5
// 7603.439 us; speedup vs baseline: 1.2275x; 1.0030x over previous
//
#include <hip/hip_runtime.h>
#include <stdint.h>

#define B_   256
#define T_   160
#define DIN_ 40
#define H_   768
#define NG_  3072   // 4*H
#define KP0_ 1024   // 48 x-pad | 768 h | pad to 1024
#define KP12_ 1536  // 768 hin | 768 hown
#define XC_  48     // padded x columns

typedef _Float16 f16;
typedef _Float16 half8 __attribute__((ext_vector_type(8)));
typedef float f32x4 __attribute__((ext_vector_type(4)));

#define AS1C(p) ((const __attribute__((address_space(1))) uint32_t*)(p))
#define AS3(p)  ((__attribute__((address_space(3))) uint32_t*)(p))

struct Params {
  const f16* wt0; const f16* wt1; const f16* wt2;
  const float* bq; const f16* x16;
  f16* hs0; f16* hs1; f16* hs2;
  const f16* zpad; unsigned* cnt; float* out;
};

__device__ __forceinline__ float sigmoid_f(float x) { return 1.f / (1.f + __expf(-x)); }
__device__ __forceinline__ float tanh_f(float x) {
  x = fminf(15.f, fmaxf(-15.f, x));
  float e = __expf(2.f * x);
  return (e - 1.f) / (e + 1.f);
}

// Weights -> fp16, transposed [n'][k], gate-interleaved cols n' = 4*j + g.
__global__ void conv_w(const float* __restrict__ Wi, const float* __restrict__ Wh,
                       int in_dim, int hoff, int Kp, f16* __restrict__ dst) {
  __shared__ f16 tile[64][66];
  const int k0 = blockIdx.x * 64;
  const int by = blockIdx.y;            // 0..47
  const int g = by / 12, j0 = (by % 12) * 64;
  const int tid = threadIdx.x;
  #pragma unroll
  for (int it = 0; it < 16; ++it) {
    int idx = it * 256 + tid;
    int jj = idx & 63;
    int kk = idx >> 6;
    int k = k0 + kk;
    int oc = g * H_ + j0 + jj;
    float v = 0.f;
    if (k < in_dim) v = Wi[(size_t)k * NG_ + oc];
    else if (k >= hoff && k < hoff + H_) v = Wh[(size_t)(k - hoff) * NG_ + oc];
    tile[kk][jj] = (f16)v;
  }
  __syncthreads();
  #pragma unroll
  for (int it = 0; it < 16; ++it) {
    int idx = it * 256 + tid;
    int kk = idx & 63;
    int jj = idx >> 6;
    int np = 4 * (j0 + jj) + g;
    dst[(size_t)np * Kp + k0 + kk] = tile[kk][jj];
  }
}

__global__ void conv_b(const float* __restrict__ b0, const float* __restrict__ b1,
                       const float* __restrict__ b2, float* __restrict__ bq) {
  int id = blockIdx.x * 256 + threadIdx.x;
  if (id < 3 * NG_) {
    int l = id / NG_, np = id % NG_;
    int j = np >> 2, g = np & 3;
    const float* s = (l == 0) ? b0 : (l == 1 ? b1 : b2);
    bq[id] = s[g * H_ + j];
  }
}

// x [B,T,40] fp32 -> x16 [T,B,48] fp16 (cols 40..47 zero)
__global__ void conv_x(const float* __restrict__ x, f16* __restrict__ x16) {
  int id = blockIdx.x * 256 + threadIdx.x;
  if (id >= T_ * B_ * XC_) return;
  int k = id % XC_;
  int b = (id / XC_) % B_;
  int t = id / (XC_ * B_);
  float v = (k < DIN_) ? x[(size_t)b * (T_ * DIN_) + t * DIN_ + k] : 0.f;
  x16[id] = (f16)v;
}

template<int L>
__device__ __forceinline__ void run_layer(
    const f16* __restrict__ WT, const f16* __restrict__ hin, f16* __restrict__ hown,
    const float* __restrict__ bql, const f16* __restrict__ zpad, float* __restrict__ out,
    unsigned* cbar, unsigned& iter, f16* Abuf, float* zred, float* bqs,
    int tid, int lane, int w, int kw, int cw, int btile, int ntile, int n0) {
  constexpr int KP  = (L == 0) ? KP0_ : KP12_;
  constexpr int KQ  = KP / 4;                 // k per wave (4-way k-split)
  constexpr int NKT = KQ / 32;                // 32-k tiles per wave: L0=8, L12=12
  constexpr int CH  = (L == 0) ? 128 : 96;    // 16B chunks per A row in addressed block

  if (tid < 96) bqs[tid] = bql[tid];

  // ---- persistent B fragments: 3 col-tiles x NKT k-tiles, 4 VGPR each (144 max)
  half8 breg[3 * NKT];
  #pragma unroll
  for (int ct = 0; ct < 3; ++ct) {
    #pragma unroll
    for (int kt = 0; kt < NKT; ++kt) {
      int col = n0 + cw * 48 + ct * 16 + (lane & 15);
      int k = kw * KQ + kt * 32 + (lane >> 4) * 8;
      breg[ct * NKT + kt] = *(const half8*)(WT + (size_t)col * KP + k);
    }
  }

  // hin staging by waves 6,7 (no gate work): 3072 chunks / 2 waves = 24 iters.
  // hin is the finished previous layer's output -> stable any time.
  auto stage_hin = [&](int slot) {
    #pragma unroll
    for (int i = 0; i < 24; ++i) {
      int cb = (w - 6) * 1536 + i * 64;
      int idx = cb + lane;
      int row = idx / 96;
      int c = idx - row * 96;
      int cg = c ^ (row & 7);
      int b = btile * 32 + row;
      const f16* src = hin + ((size_t)slot * B_ + b) * H_ + cg * 8;
      __builtin_amdgcn_global_load_lds(AS1C(src), AS3(Abuf + (size_t)cb * 8), 16, 0, 0);
    }
  };
  if (L > 0 && tid >= 384) stage_hin(1);   // h_{l-1}(0) for step 0

  // one gate item per thread (tid<384): item id = row*12+jp; 8 gate cols = 2 h cols
  const int id = tid;
  const int grow = id / 12, gjp = id - grow * 12;
  const int gb = btile * 32 + grow;
  const int ghc0 = ntile * 24 + 2 * gjp;
  float c0 = 0.f, c1 = 0.f, oa0 = 0.f, oa1 = 0.f;

  for (int t = 0; t < T_; ++t) {
    // ---- step-start staging
    if (L == 0) {
      // full A tile 32x1024 f16 = 4096 chunks over 8 waves
      #pragma unroll
      for (int i = 0; i < 8; ++i) {
        int cb = w * 512 + i * 64;
        int idx = cb + lane;
        int row = idx >> 7;
        int c = idx & 127;
        int cg = c ^ (row & 7);
        int b = btile * 32 + row;
        const f16* src;
        if (cg < 6)        src = hin + ((size_t)t * B_ + b) * XC_ + cg * 8;   // x16
        else if (cg < 102) src = hown + ((size_t)t * B_ + b) * H_ + (cg - 6) * 8;
        else               src = zpad;
        __builtin_amdgcn_global_load_lds(AS1C(src), AS3(Abuf + (size_t)cb * 8), 16, 0, 0);
      }
    } else if (w >= 4) {
      // hown(t-1) half: 3072 chunks over waves 4-7 = 12 iters
      #pragma unroll
      for (int i = 0; i < 12; ++i) {
        int cb = (w - 4) * 768 + i * 64;
        int idx = cb + lane;
        int row = idx / 96;
        int c = idx - row * 96;
        int cg = c ^ (row & 7);
        int b = btile * 32 + row;
        const f16* src = hown + ((size_t)t * B_ + b) * H_ + cg * 8;
        __builtin_amdgcn_global_load_lds(AS1C(src), AS3(Abuf + (size_t)(32 * 768 + cb * 8)), 16, 0, 0);
      }
    }
    asm volatile("s_waitcnt vmcnt(0)" ::: "memory");
    __syncthreads();

    // ---- MFMA: wave tile 32 rows x 48 cols over its k-quarter
    f32x4 acc[2][3] = {};
    const char* Ab = (const char*)(Abuf + (L == 0 ? 0 : (kw >> 1) * 32 * 768));
    const int cbase = (L == 0) ? kw * 32 : (kw & 1) * 48;
    #pragma unroll
    for (int kt = 0; kt < NKT; ++kt) {
      int c = cbase + kt * 4 + (lane >> 4);
      int row0 = (lane & 15);
      half8 a0 = *(const half8*)(Ab + (size_t)row0 * (CH * 16) + (size_t)(c ^ (row0 & 7)) * 16);
      int row1 = 16 + (lane & 15);
      half8 a1 = *(const half8*)(Ab + (size_t)row1 * (CH * 16) + (size_t)(c ^ (row1 & 7)) * 16);
      #pragma unroll
      for (int ct = 0; ct < 3; ++ct) {
        acc[0][ct] = __builtin_amdgcn_mfma_f32_16x16x32_f16(a0, breg[ct * NKT + kt], acc[0][ct], 0, 0, 0);
        acc[1][ct] = __builtin_amdgcn_mfma_f32_16x16x32_f16(a1, breg[ct * NKT + kt], acc[1][ct], 0, 0, 0);
      }
    }

    // ---- partial Z -> LDS, stride-96 layout: addr = kw*3072 + row*96 + col
    {
      float* zr = zred + kw * 3072;
      #pragma unroll
      for (int rt = 0; rt < 2; ++rt) {
        #pragma unroll
        for (int ct = 0; ct < 3; ++ct) {
          int row = rt * 16 + (lane >> 4) * 4;
          int col = cw * 48 + ct * 16 + (lane & 15);
          #pragma unroll
          for (int r4 = 0; r4 < 4; ++r4)
            zr[(size_t)(row + r4) * 96 + col] = acc[rt][ct][r4];
        }
      }
    }
    __syncthreads();

    // ---- waves 6,7: prefetch hin(t+1)'s slot (t+2) while others do gates
    if (tid >= 384) {
      if (L > 0 && t + 1 < T_) stage_hin(t + 2);
    } else {
      // gate item: reads are lane-linear (id*8 dwords) -> conflict-free
      const float* z = zred + (size_t)id * 8;
      f32x4 za = *(const f32x4*)(z)        + *(const f32x4*)(z + 3072)
               + *(const f32x4*)(z + 6144) + *(const f32x4*)(z + 9216);
      f32x4 zb = *(const f32x4*)(z + 4)        + *(const f32x4*)(z + 3076)
               + *(const f32x4*)(z + 6148)     + *(const f32x4*)(z + 9220);
      za += *(const f32x4*)(bqs + gjp * 8);
      zb += *(const f32x4*)(bqs + gjp * 8 + 4);
      float i0 = sigmoid_f(za[0]), f0 = sigmoid_f(za[1]), g0 = tanh_f(za[2]), o0 = sigmoid_f(za[3]);
      float i1 = sigmoid_f(zb[0]), f1 = sigmoid_f(zb[1]), g1 = tanh_f(zb[2]), o1 = sigmoid_f(zb[3]);
      float cn0 = f0 * c0 + i0 * g0;
      float cn1 = f1 * c1 + i1 * g1;
      c0 = cn0; c1 = cn1;
      float h0 = o0 * tanh_f(cn0);
      float h1 = o1 * tanh_f(cn1);
      f16 hh0 = (f16)h0, hh1 = (f16)h1;
      unsigned u = ((unsigned)__builtin_bit_cast(uint16_t, hh1) << 16)
                 |  (unsigned)__builtin_bit_cast(uint16_t, hh0);
      unsigned* hp = (unsigned*)(hown + ((size_t)(t + 1) * B_ + gb) * H_ + ghc0);
      __hip_atomic_store(hp, u, __ATOMIC_RELAXED, __HIP_MEMORY_SCOPE_AGENT);
      if (L == 2) {
        oa0 += h0; oa1 += h1;
        if (t == T_ - 1) {
          out[(size_t)gb * H_ + ghc0]     = oa0 * (1.f / T_);
          out[(size_t)gb * H_ + ghc0 + 1] = oa1 * (1.f / T_);
        }
      }
    }

    // ---- drain h-stores (gate waves only; prefetch waves keep loads in flight)
    if (tid < 384) { asm volatile("s_waitcnt vmcnt(0)" ::: "memory"); }
    __syncthreads();
    ++iter;
    if (tid == 383) {  // master in wave 5: fully drained, no prefetch outstanding
      __hip_atomic_fetch_add(cbar, 1u, __ATOMIC_RELEASE, __HIP_MEMORY_SCOPE_AGENT);
      while (__hip_atomic_load(cbar, __ATOMIC_RELAXED, __HIP_MEMORY_SCOPE_AGENT) < 32u * iter)
        __builtin_amdgcn_s_sleep(2);
    }
    __syncthreads();
  }
}

__global__ __launch_bounds__(512, 2) void lstm_main(Params p) {
  __shared__ __align__(16) f16 Abuf[2 * 32 * 768];        // 96 KB
  __shared__ __align__(16) float zred[4 * 32 * 96];       // 48 KB (4 k-partials)
  __shared__ __align__(16) float bqs[96];

  const int tid = threadIdx.x;
  const int lane = tid & 63;
  const int w = tid >> 6;                  // 0..7
  const int kw = w >> 1, cw = w & 1;       // k-quarter 0..3, col-half 0..1
  const int bid = blockIdx.x;
  // contiguous group mapping: group = 32 consecutive bids (liveness under
  // sequential dispatch even if not all 256 WGs are co-resident)
  const int btile = bid >> 5;              // 0..7
  const int ntile = bid & 31;              // 0..31
  unsigned* cbar = p.cnt + btile * 32;
  const int n0 = ntile * 96;
  unsigned iter = 0;

  run_layer<0>(p.wt0, p.x16, p.hs0, p.bq + 0 * NG_ + n0, p.zpad, p.out, cbar, iter,
               Abuf, zred, bqs, tid, lane, w, kw, cw, btile, ntile, n0);
  run_layer<1>(p.wt1, p.hs0, p.hs1, p.bq + 1 * NG_ + n0, p.zpad, p.out, cbar, iter,
               Abuf, zred, bqs, tid, lane, w, kw, cw, btile, ntile, n0);
  run_layer<2>(p.wt2, p.hs1, p.hs2, p.bq + 2 * NG_ + n0, p.zpad, p.out, cbar, iter,
               Abuf, zred, bqs, tid, lane, w, kw, cw, btile, ntile, n0);
}

extern "C" void kernel_launch(void* const* d_in, const int* in_sizes, int n_in,
                              void* d_out, int out_size, void* d_ws, size_t ws_size,
                              hipStream_t stream) {
  const float* x   = (const float*)d_in[0];
  const float* Wi0 = (const float*)d_in[1];
  const float* Wh0 = (const float*)d_in[2];
  const float* b0  = (const float*)d_in[3];
  const float* Wi1 = (const float*)d_in[4];
  const float* Wh1 = (const float*)d_in[5];
  const float* b1  = (const float*)d_in[6];
  const float* Wi2 = (const float*)d_in[7];
  const float* Wh2 = (const float*)d_in[8];
  const float* b2  = (const float*)d_in[9];

  char* wsb = (char*)d_ws;
  size_t off = 0;
  auto nxt = [&](size_t sz) { char* p = wsb + off; off += (sz + 255) & ~(size_t)255; return p; };
  f16*      wt0  = (f16*)nxt((size_t)NG_ * KP0_ * 2);         // 6.3 MB
  f16*      wt1  = (f16*)nxt((size_t)NG_ * KP12_ * 2);        // 9.4 MB
  f16*      wt2  = (f16*)nxt((size_t)NG_ * KP12_ * 2);        // 9.4 MB
  float*    bq   = (float*)nxt((size_t)3 * NG_ * 4);
  f16*      x16  = (f16*)nxt((size_t)T_ * B_ * XC_ * 2);      // 3.9 MB
  f16*      hs0  = (f16*)nxt((size_t)(T_ + 1) * B_ * H_ * 2); // 60.4 MB
  f16*      hs1  = (f16*)nxt((size_t)(T_ + 1) * B_ * H_ * 2);
  f16*      hs2  = (f16*)nxt((size_t)(T_ + 1) * B_ * H_ * 2);
  f16*      zpad = (f16*)nxt(256);
  unsigned* cnt  = (unsigned*)nxt(1024);
  if (off > ws_size) return;  // insufficient workspace

  const size_t slot_bytes = (size_t)B_ * H_ * 2;
  hipMemsetAsync(hs0, 0, slot_bytes, stream);
  hipMemsetAsync(hs1, 0, slot_bytes, stream);
  hipMemsetAsync(hs2, 0, slot_bytes, stream);
  hipMemsetAsync((void*)zpad, 0, 256, stream);
  hipMemsetAsync(cnt, 0, 1024, stream);

  hipLaunchKernelGGL(conv_w, dim3(KP0_ / 64, 48), dim3(256), 0, stream, Wi0, Wh0, DIN_, XC_, KP0_, wt0);
  hipLaunchKernelGGL(conv_w, dim3(KP12_ / 64, 48), dim3(256), 0, stream, Wi1, Wh1, H_, H_, KP12_, wt1);
  hipLaunchKernelGGL(conv_w, dim3(KP12_ / 64, 48), dim3(256), 0, stream, Wi2, Wh2, H_, H_, KP12_, wt2);
  hipLaunchKernelGGL(conv_b, dim3((3 * NG_ + 255) / 256), dim3(256), 0, stream, b0, b1, b2, bq);
  hipLaunchKernelGGL(conv_x, dim3((T_ * B_ * XC_ + 255) / 256), dim3(256), 0, stream, x, x16);

  Params prm{wt0, wt1, wt2, bq, x16, hs0, hs1, hs2, zpad, cnt, (float*)d_out};
  // Plain launch (NOT cooperative): only the 8 independent 32-WG group
  // barriers are used; cooperative-launch validation rejected big-LDS kernels.
  hipLaunchKernelGGL(lstm_main, dim3(256), dim3(512), 0, stream, prm);
}

// Round 6
// 6005.460 us; speedup vs baseline: 1.5541x; 1.2661x over previous
//
#include <hip/hip_runtime.h>
#include <stdint.h>

#define B_   256
#define T_   160
#define DIN_ 40
#define H_   768
#define NG_  3072   // 4*H
#define KP0_ 1024   // 48 x-pad | 768 h | pad to 1024
#define KP12_ 1536  // 768 hin | 768 hown
#define XC_  48     // padded x columns

typedef _Float16 f16;
typedef _Float16 half8 __attribute__((ext_vector_type(8)));
typedef float f32x4 __attribute__((ext_vector_type(4)));

#define AS1C(p) ((const __attribute__((address_space(1))) uint32_t*)(p))
#define AS3(p)  ((__attribute__((address_space(3))) uint32_t*)(p))

struct Params {
  const f16* wt0; const f16* wt1; const f16* wt2;
  const float* bq; const f16* x16;
  f16* hs0; f16* hs1; f16* hs2;
  const f16* zpad; unsigned* cnt; float* out;
};

__device__ __forceinline__ float sigmoid_f(float x) { return 1.f / (1.f + __expf(-x)); }
__device__ __forceinline__ float tanh_f(float x) {
  x = fminf(15.f, fmaxf(-15.f, x));
  float e = __expf(2.f * x);
  return (e - 1.f) / (e + 1.f);
}

// Weights -> fp16, transposed [n'][k], gate-interleaved cols n' = 4*j + g.
__global__ void conv_w(const float* __restrict__ Wi, const float* __restrict__ Wh,
                       int in_dim, int hoff, int Kp, f16* __restrict__ dst) {
  __shared__ f16 tile[64][66];
  const int k0 = blockIdx.x * 64;
  const int by = blockIdx.y;            // 0..47
  const int g = by / 12, j0 = (by % 12) * 64;
  const int tid = threadIdx.x;
  #pragma unroll
  for (int it = 0; it < 16; ++it) {
    int idx = it * 256 + tid;
    int jj = idx & 63;
    int kk = idx >> 6;
    int k = k0 + kk;
    int oc = g * H_ + j0 + jj;
    float v = 0.f;
    if (k < in_dim) v = Wi[(size_t)k * NG_ + oc];
    else if (k >= hoff && k < hoff + H_) v = Wh[(size_t)(k - hoff) * NG_ + oc];
    tile[kk][jj] = (f16)v;
  }
  __syncthreads();
  #pragma unroll
  for (int it = 0; it < 16; ++it) {
    int idx = it * 256 + tid;
    int kk = idx & 63;
    int jj = idx >> 6;
    int np = 4 * (j0 + jj) + g;
    dst[(size_t)np * Kp + k0 + kk] = tile[kk][jj];
  }
}

__global__ void conv_b(const float* __restrict__ b0, const float* __restrict__ b1,
                       const float* __restrict__ b2, float* __restrict__ bq) {
  int id = blockIdx.x * 256 + threadIdx.x;
  if (id < 3 * NG_) {
    int l = id / NG_, np = id % NG_;
    int j = np >> 2, g = np & 3;
    const float* s = (l == 0) ? b0 : (l == 1 ? b1 : b2);
    bq[id] = s[g * H_ + j];
  }
}

// x [B,T,40] fp32 -> x16 [T,B,48] fp16 (cols 40..47 zero)
__global__ void conv_x(const float* __restrict__ x, f16* __restrict__ x16) {
  int id = blockIdx.x * 256 + threadIdx.x;
  if (id >= T_ * B_ * XC_) return;
  int k = id % XC_;
  int b = (id / XC_) % B_;
  int t = id / (XC_ * B_);
  float v = (k < DIN_) ? x[(size_t)b * (T_ * DIN_) + t * DIN_ + k] : 0.f;
  x16[id] = (f16)v;
}

template<int L>
__device__ __forceinline__ void run_layer(
    const f16* __restrict__ WT, const f16* __restrict__ hin, f16* __restrict__ hown,
    const float* __restrict__ bql, const f16* __restrict__ zpad, float* __restrict__ out,
    unsigned* cbar, unsigned& iter, f16* Abuf, float* zred, float* bqs,
    int tid, int lane, int w, int kw, int cw, int btile, int ntile, int n0) {
  constexpr int KP  = (L == 0) ? KP0_ : KP12_;
  constexpr int KQ  = KP / 4;                 // k per wave (4-way k-split)
  constexpr int NKT = KQ / 32;                // 32-k tiles per wave: L0=8, L12=12
  constexpr int CH  = (L == 0) ? 128 : 96;    // 16B chunks per A row in addressed block

  if (tid < 96) bqs[tid] = bql[tid];

  // ---- persistent B fragments: 3 col-tiles x NKT k-tiles, 4 VGPR each (144 max)
  half8 breg[3 * NKT];
  #pragma unroll
  for (int ct = 0; ct < 3; ++ct) {
    #pragma unroll
    for (int kt = 0; kt < NKT; ++kt) {
      int col = n0 + cw * 48 + ct * 16 + (lane & 15);
      int k = kw * KQ + kt * 32 + (lane >> 4) * 8;
      breg[ct * NKT + kt] = *(const half8*)(WT + (size_t)col * KP + k);
    }
  }

  // hin staging by waves 6,7 (no gate work): 3072 chunks / 2 waves = 24 iters.
  // hin is the finished previous layer's output -> stable any time.
  auto stage_hin = [&](int slot) {
    #pragma unroll
    for (int i = 0; i < 24; ++i) {
      int cb = (w - 6) * 1536 + i * 64;
      int idx = cb + lane;
      int row = idx / 96;
      int c = idx - row * 96;
      int cg = c ^ (row & 7);
      int b = btile * 32 + row;
      const f16* src = hin + ((size_t)slot * B_ + b) * H_ + cg * 8;
      __builtin_amdgcn_global_load_lds(AS1C(src), AS3(Abuf + (size_t)cb * 8), 16, 0, 0);
    }
  };
  if (L > 0 && tid >= 384) stage_hin(1);   // h_{l-1}(0) for step 0

  // one gate item per thread (tid<384): item id = row*12+jp; 8 gate cols = 2 h cols
  const int id = tid;
  const int grow = id / 12, gjp = id - grow * 12;
  const int gb = btile * 32 + grow;
  const int ghc0 = ntile * 24 + 2 * gjp;
  float c0 = 0.f, c1 = 0.f, oa0 = 0.f, oa1 = 0.f;

  for (int t = 0; t < T_; ++t) {
    // ---- step-start staging
    if (L == 0) {
      // full A tile 32x1024 f16 = 4096 chunks over 8 waves
      #pragma unroll
      for (int i = 0; i < 8; ++i) {
        int cb = w * 512 + i * 64;
        int idx = cb + lane;
        int row = idx >> 7;
        int c = idx & 127;
        int cg = c ^ (row & 7);
        int b = btile * 32 + row;
        const f16* src;
        if (cg < 6)        src = hin + ((size_t)t * B_ + b) * XC_ + cg * 8;   // x16
        else if (cg < 102) src = hown + ((size_t)t * B_ + b) * H_ + (cg - 6) * 8;
        else               src = zpad;
        __builtin_amdgcn_global_load_lds(AS1C(src), AS3(Abuf + (size_t)cb * 8), 16, 0, 0);
      }
    } else if (w >= 4) {
      // hown(t-1) half: 3072 chunks over waves 4-7 = 12 iters
      #pragma unroll
      for (int i = 0; i < 12; ++i) {
        int cb = (w - 4) * 768 + i * 64;
        int idx = cb + lane;
        int row = idx / 96;
        int c = idx - row * 96;
        int cg = c ^ (row & 7);
        int b = btile * 32 + row;
        const f16* src = hown + ((size_t)t * B_ + b) * H_ + cg * 8;
        __builtin_amdgcn_global_load_lds(AS1C(src), AS3(Abuf + (size_t)(32 * 768 + cb * 8)), 16, 0, 0);
      }
    }
    asm volatile("s_waitcnt vmcnt(0)" ::: "memory");
    __syncthreads();

    // ---- MFMA: wave tile 32 rows x 48 cols over its k-quarter
    f32x4 acc[2][3] = {};
    const char* Ab = (const char*)(Abuf + (L == 0 ? 0 : (kw >> 1) * 32 * 768));
    const int cbase = (L == 0) ? kw * 32 : (kw & 1) * 48;
    #pragma unroll
    for (int kt = 0; kt < NKT; ++kt) {
      int c = cbase + kt * 4 + (lane >> 4);
      int row0 = (lane & 15);
      half8 a0 = *(const half8*)(Ab + (size_t)row0 * (CH * 16) + (size_t)(c ^ (row0 & 7)) * 16);
      int row1 = 16 + (lane & 15);
      half8 a1 = *(const half8*)(Ab + (size_t)row1 * (CH * 16) + (size_t)(c ^ (row1 & 7)) * 16);
      #pragma unroll
      for (int ct = 0; ct < 3; ++ct) {
        acc[0][ct] = __builtin_amdgcn_mfma_f32_16x16x32_f16(a0, breg[ct * NKT + kt], acc[0][ct], 0, 0, 0);
        acc[1][ct] = __builtin_amdgcn_mfma_f32_16x16x32_f16(a1, breg[ct * NKT + kt], acc[1][ct], 0, 0, 0);
      }
    }

    // ---- partial Z -> LDS, stride-96 layout: addr = kw*3072 + row*96 + col
    {
      float* zr = zred + kw * 3072;
      #pragma unroll
      for (int rt = 0; rt < 2; ++rt) {
        #pragma unroll
        for (int ct = 0; ct < 3; ++ct) {
          int row = rt * 16 + (lane >> 4) * 4;
          int col = cw * 48 + ct * 16 + (lane & 15);
          #pragma unroll
          for (int r4 = 0; r4 < 4; ++r4)
            zr[(size_t)(row + r4) * 96 + col] = acc[rt][ct][r4];
        }
      }
    }
    __syncthreads();

    // ---- waves 6,7: prefetch hin(t+1)'s slot (t+2) while others do gates
    if (tid >= 384) {
      if (L > 0 && t + 1 < T_) stage_hin(t + 2);
    } else {
      // gate item: reads are lane-linear (id*8 dwords) -> conflict-free
      const float* z = zred + (size_t)id * 8;
      f32x4 za = *(const f32x4*)(z)        + *(const f32x4*)(z + 3072)
               + *(const f32x4*)(z + 6144) + *(const f32x4*)(z + 9216);
      f32x4 zb = *(const f32x4*)(z + 4)        + *(const f32x4*)(z + 3076)
               + *(const f32x4*)(z + 6148)     + *(const f32x4*)(z + 9220);
      za += *(const f32x4*)(bqs + gjp * 8);
      zb += *(const f32x4*)(bqs + gjp * 8 + 4);
      float i0 = sigmoid_f(za[0]), f0 = sigmoid_f(za[1]), g0 = tanh_f(za[2]), o0 = sigmoid_f(za[3]);
      float i1 = sigmoid_f(zb[0]), f1 = sigmoid_f(zb[1]), g1 = tanh_f(zb[2]), o1 = sigmoid_f(zb[3]);
      float cn0 = f0 * c0 + i0 * g0;
      float cn1 = f1 * c1 + i1 * g1;
      c0 = cn0; c1 = cn1;
      float h0 = o0 * tanh_f(cn0);
      float h1 = o1 * tanh_f(cn1);
      f16 hh0 = (f16)h0, hh1 = (f16)h1;
      unsigned u = ((unsigned)__builtin_bit_cast(uint16_t, hh1) << 16)
                 |  (unsigned)__builtin_bit_cast(uint16_t, hh0);
      unsigned* hp = (unsigned*)(hown + ((size_t)(t + 1) * B_ + gb) * H_ + ghc0);
      __hip_atomic_store(hp, u, __ATOMIC_RELAXED, __HIP_MEMORY_SCOPE_AGENT);
      if (L == 2) {
        oa0 += h0; oa1 += h1;
        if (t == T_ - 1) {
          out[(size_t)gb * H_ + ghc0]     = oa0 * (1.f / T_);
          out[(size_t)gb * H_ + ghc0 + 1] = oa1 * (1.f / T_);
        }
      }
    }

    // ---- drain h-stores (gate waves only; prefetch waves keep loads in flight)
    if (tid < 384) { asm volatile("s_waitcnt vmcnt(0)" ::: "memory"); }
    __syncthreads();
    ++iter;
    // ---- distributed RMW-free group barrier:
    // arrive: one sc1 store of monotone `iter` to THIS WG's private 128B line
    // (ordering vs h-stores: per-wave vmcnt(0) above + s_barrier).
    // wait: wave 5 gather-polls all 32 flags with one 32-lane vector load.
    if (w == 5) {
      if (lane == 0)
        __hip_atomic_store(cbar + (size_t)ntile * 32, iter,
                           __ATOMIC_RELAXED, __HIP_MEMORY_SCOPE_AGENT);
      unsigned* fp = cbar + (size_t)(lane & 31) * 32;
      for (;;) {
        unsigned v = __hip_atomic_load(fp, __ATOMIC_RELAXED, __HIP_MEMORY_SCOPE_AGENT);
        if (__ballot(v >= iter) == ~0ull) break;
        __builtin_amdgcn_s_sleep(1);
      }
    }
    __syncthreads();
  }
}

__global__ __launch_bounds__(512, 2) void lstm_main(Params p) {
  __shared__ __align__(16) f16 Abuf[2 * 32 * 768];        // 96 KB
  __shared__ __align__(16) float zred[4 * 32 * 96];       // 48 KB (4 k-partials)
  __shared__ __align__(16) float bqs[96];

  const int tid = threadIdx.x;
  const int lane = tid & 63;
  const int w = tid >> 6;                  // 0..7
  const int kw = w >> 1, cw = w & 1;       // k-quarter 0..3, col-half 0..1
  const int bid = blockIdx.x;
  // contiguous group mapping: group = 32 consecutive bids (liveness under
  // sequential dispatch even if not all 256 WGs are co-resident)
  const int btile = bid >> 5;              // 0..7
  const int ntile = bid & 31;              // 0..31
  unsigned* cbar = p.cnt + (size_t)btile * 1024;   // 32 flags x 128B stride
  const int n0 = ntile * 96;
  unsigned iter = 0;

  run_layer<0>(p.wt0, p.x16, p.hs0, p.bq + 0 * NG_ + n0, p.zpad, p.out, cbar, iter,
               Abuf, zred, bqs, tid, lane, w, kw, cw, btile, ntile, n0);
  run_layer<1>(p.wt1, p.hs0, p.hs1, p.bq + 1 * NG_ + n0, p.zpad, p.out, cbar, iter,
               Abuf, zred, bqs, tid, lane, w, kw, cw, btile, ntile, n0);
  run_layer<2>(p.wt2, p.hs1, p.hs2, p.bq + 2 * NG_ + n0, p.zpad, p.out, cbar, iter,
               Abuf, zred, bqs, tid, lane, w, kw, cw, btile, ntile, n0);
}

extern "C" void kernel_launch(void* const* d_in, const int* in_sizes, int n_in,
                              void* d_out, int out_size, void* d_ws, size_t ws_size,
                              hipStream_t stream) {
  const float* x   = (const float*)d_in[0];
  const float* Wi0 = (const float*)d_in[1];
  const float* Wh0 = (const float*)d_in[2];
  const float* b0  = (const float*)d_in[3];
  const float* Wi1 = (const float*)d_in[4];
  const float* Wh1 = (const float*)d_in[5];
  const float* b1  = (const float*)d_in[6];
  const float* Wi2 = (const float*)d_in[7];
  const float* Wh2 = (const float*)d_in[8];
  const float* b2  = (const float*)d_in[9];

  char* wsb = (char*)d_ws;
  size_t off = 0;
  auto nxt = [&](size_t sz) { char* p = wsb + off; off += (sz + 255) & ~(size_t)255; return p; };
  f16*      wt0  = (f16*)nxt((size_t)NG_ * KP0_ * 2);         // 6.3 MB
  f16*      wt1  = (f16*)nxt((size_t)NG_ * KP12_ * 2);        // 9.4 MB
  f16*      wt2  = (f16*)nxt((size_t)NG_ * KP12_ * 2);        // 9.4 MB
  float*    bq   = (float*)nxt((size_t)3 * NG_ * 4);
  f16*      x16  = (f16*)nxt((size_t)T_ * B_ * XC_ * 2);      // 3.9 MB
  f16*      hs0  = (f16*)nxt((size_t)(T_ + 1) * B_ * H_ * 2); // 60.4 MB
  f16*      hs1  = (f16*)nxt((size_t)(T_ + 1) * B_ * H_ * 2);
  f16*      hs2  = (f16*)nxt((size_t)(T_ + 1) * B_ * H_ * 2);
  f16*      zpad = (f16*)nxt(256);
  unsigned* cnt  = (unsigned*)nxt(8 * 1024 * 4);              // 8 groups x 32 flags x 128B
  if (off > ws_size) return;  // insufficient workspace

  const size_t slot_bytes = (size_t)B_ * H_ * 2;
  hipMemsetAsync(hs0, 0, slot_bytes, stream);
  hipMemsetAsync(hs1, 0, slot_bytes, stream);
  hipMemsetAsync(hs2, 0, slot_bytes, stream);
  hipMemsetAsync((void*)zpad, 0, 256, stream);
  hipMemsetAsync(cnt, 0, 8 * 1024 * 4, stream);

  hipLaunchKernelGGL(conv_w, dim3(KP0_ / 64, 48), dim3(256), 0, stream, Wi0, Wh0, DIN_, XC_, KP0_, wt0);
  hipLaunchKernelGGL(conv_w, dim3(KP12_ / 64, 48), dim3(256), 0, stream, Wi1, Wh1, H_, H_, KP12_, wt1);
  hipLaunchKernelGGL(conv_w, dim3(KP12_ / 64, 48), dim3(256), 0, stream, Wi2, Wh2, H_, H_, KP12_, wt2);
  hipLaunchKernelGGL(conv_b, dim3((3 * NG_ + 255) / 256), dim3(256), 0, stream, b0, b1, b2, bq);
  hipLaunchKernelGGL(conv_x, dim3((T_ * B_ * XC_ + 255) / 256), dim3(256), 0, stream, x, x16);

  Params prm{wt0, wt1, wt2, bq, x16, hs0, hs1, hs2, zpad, cnt, (float*)d_out};
  // Plain launch (NOT cooperative): only the 8 independent 32-WG group
  // barriers are used; cooperative-launch validation rejected big-LDS kernels.
  hipLaunchKernelGGL(lstm_main, dim3(256), dim3(512), 0, stream, prm);
}